// Round 5
// 1493.408 us; speedup vs baseline: 1.0992x; 1.0992x over previous
//
#include <hip/hip_runtime.h>
#include <hip/hip_fp16.h>

// ---------------------------------------------------------------------------
// 2-layer tanh RNN, B=256, T=512, H=512, D=64, + FC(512->1).
//   proj0:  P[b,t,:] = x[b,t,:] @ W_ih0^T + (b_ih0+b_hh0)     (MFMA f16, K=64)
//   rec0:   per-CU recurrence via M=1 MFMA, writes h1 in place over P
//   proj1:  P[b,t,:] = h1[b,t,:] @ W_ih1^T + (b_ih1+b_hh1)    (in-place)
//   rec1:   recurrence + final FC -> d_out[256]
//
// Round 9: revert to the round-4 PASSING build (1641 us) + two surgical tail
// optimizations (rounds 5-8's M=16 pipeline rewrite NaN'd even with zero
// cross-block sync -> bug is in that machinery; abandoned for now):
//   (1) hxch LDS round-trip DELETED. With broadcast-A (all 16 rows equal),
//       every lane's acc[g][0] holds col 16g+(l&15); lane l needs g = l>>4,
//       i.e. h[64w+l] = acc[l>>4][0] -- already in-lane. Select via cndmask
//       chain (NOT acc[lq]: runtime-indexed arrays go to scratch).
//       Cuts ds_write+lgkmcnt+ds_read (~240+ cy) off the serial per-step tail.
//   (2) tanhf -> 1 - 2*rcp(exp(2s)+1) via __expf (~30 fewer serial VALU cy).
//
// rec engine (round 4): one chain per CU, 512 threads = 8 waves = 2 waves/SIMD.
// Per wave: n-slice 64 = 4 tiles x 16 ksteps = 64 MFMAs/step. Weights per wave:
//   32 frags pinned to AGPRs (asm "a"), 14 frags in VGPRs, 18 frags in LDS.
// One barrier per step; double-buffered hbuf.
// ---------------------------------------------------------------------------

typedef _Float16 h2 __attribute__((ext_vector_type(2)));
typedef _Float16 h8 __attribute__((ext_vector_type(8)));
typedef float    f4 __attribute__((ext_vector_type(4)));

#define HID   512
#define TSEQ  512
#define NB    256
#define NWAVE 8
#define NAG   32    // AGPR frags per wave (slots 0..31, interleaved 2 per kstep)
#define NVG   14    // VGPR frags per wave (slots 32..45)
#define NREGF (NAG + NVG)   // 46
#define NLDSF 18    // LDS frags per wave

// D = A*B + D;  B pinned to AGPR / VGPR respectively.
#define MFMA_A(accv, av, bv) \
  asm("v_mfma_f32_16x16x32_f16 %0, %1, %2, %0" : "+v"(accv) : "v"(av), "a"(bv))
#define MFMA_V(accv, av, bv) \
  asm("v_mfma_f32_16x16x32_f16 %0, %1, %2, %0" : "+v"(accv) : "v"(av), "v"(bv))

#if __has_builtin(__builtin_amdgcn_rcpf)
#define FAST_RCP(x) __builtin_amdgcn_rcpf(x)
#else
#define FAST_RCP(x) (1.0f / (x))
#endif

// ---------------- workspace layout (bytes) ----------------
static const size_t OFF_P   = 0;                       // [131072][512] fp16  134217728
static const size_t OFF_B0  = 134217728;               // W_ih0 fp16 [512][64]    65536
static const size_t OFF_B1  = OFF_B0 + 65536;          // W_ih1 fp16 [512][512]  524288
static const size_t OFF_R0  = OFF_B1 + 524288;         // 8*46*64*16 = 376832
static const size_t OFF_L0  = OFF_R0 + 376832;         // 8*18*64*16 = 147456
static const size_t OFF_R1  = OFF_L0 + 147456;
static const size_t OFF_L1  = OFF_R1 + 376832;
static const size_t OFF_BS0 = OFF_L1 + 147456;         // bias0 f32 [512]
static const size_t OFF_BS1 = OFF_BS0 + 2048;          // bias1 f32 [512]

// ---------------- prep kernels ----------------
__global__ void bias_kernel(const float* __restrict__ bih0, const float* __restrict__ bhh0,
                            const float* __restrict__ bih1, const float* __restrict__ bhh1,
                            float* __restrict__ bias0, float* __restrict__ bias1) {
  int i = threadIdx.x;  // block 512
  bias0[i] = bih0[i] + bhh0[i];
  bias1[i] = bih1[i] + bhh1[i];
}

__global__ void cvt_half_kernel(const float* __restrict__ in, _Float16* __restrict__ outp, int n) {
  int i = blockIdx.x * 256 + threadIdx.x;
  if (i < n) outp[i] = (_Float16)in[i];
}

// Pack W_hh (fp32 [512][512]) into MFMA B-fragment order for the 8-wave rec.
// Fragment (wave w in 0..7, tile g in 0..3, kstep kk in 0..15), lane l:
//   8 halfs = W[64w + 16g + (l&15)][32kk + (l>>4)*8 .. +8)
// Pools: g 0/1 -> reg slot 2kk+g (AGPR); g2 -> kk<14 ? reg 32+kk : lds 16+(kk-14);
//        g3 -> lds kk.
__global__ void pack_rec_kernel(const float* __restrict__ W, uint4* __restrict__ BregP,
                                uint4* __restrict__ BldsP) {
  int t = blockIdx.x * 256 + threadIdx.x;   // 32768 threads
  int l  = t & 63;
  int g  = (t >> 6) & 3;
  int kk = (t >> 8) & 15;
  int w  = (t >> 12) & 7;
  int n  = 64 * w + 16 * g + (l & 15);
  int k0 = 32 * kk + ((l >> 4) & 3) * 8;
  const float* src = W + (size_t)n * HID + k0;
  h8 v;
#pragma unroll
  for (int i = 0; i < 8; ++i) v[i] = (_Float16)src[i];
  uint4 u = __builtin_bit_cast(uint4, v);
  if (g < 2) {
    BregP[(w * NREGF + 2 * kk + g) * 64 + l] = u;
  } else if (g == 2) {
    if (kk < 14) BregP[(w * NREGF + NAG + kk) * 64 + l] = u;
    else         BldsP[(w * NLDSF + 16 + (kk - 14)) * 64 + l] = u;
  } else {
    BldsP[(w * NLDSF + kk) * 64 + l] = u;
  }
}

// ---------------- projection GEMM (MFMA f16) ----------------
template <typename AT, int K>
__global__ __launch_bounds__(256, 2) void proj_kernel(const AT* A, const _Float16* __restrict__ Bw,
                                                      _Float16* C, const float* __restrict__ bias) {
  __shared__ _Float16 At[64][40];
  __shared__ _Float16 Bt[512][40];
  const int tid = threadIdx.x;
  const int m0 = blockIdx.x * 64;
  const int wv = tid >> 6;
  const int l = tid & 63;
  const int n0 = wv * 128;
  const int lm = l & 15;
  const int lq = l >> 4;

  f4 acc[4][8];
#pragma unroll
  for (int i = 0; i < 4; ++i)
#pragma unroll
    for (int j = 0; j < 8; ++j) acc[i][j] = (f4){0.f, 0.f, 0.f, 0.f};

  const int arow = tid >> 2;
  const int kq = (tid & 3) * 8;

  for (int k0 = 0; k0 < K; k0 += 32) {
    if (sizeof(AT) == 4) {
      const float* ap = (const float*)A + (size_t)(m0 + arow) * K + k0 + kq;
      h8 v;
#pragma unroll
      for (int i = 0; i < 8; ++i) v[i] = (_Float16)ap[i];
      *(h8*)&At[arow][kq] = v;
    } else {
      *(h8*)&At[arow][kq] = *(const h8*)((const _Float16*)A + (size_t)(m0 + arow) * K + k0 + kq);
    }
#pragma unroll
    for (int rr = 0; rr < 8; ++rr) {
      int rrow = arow + rr * 64;
      *(h8*)&Bt[rrow][kq] = *(const h8*)(Bw + (size_t)rrow * K + k0 + kq);
    }
    __syncthreads();
    h8 af[4];
#pragma unroll
    for (int mm = 0; mm < 4; ++mm) af[mm] = *(const h8*)&At[mm * 16 + lm][lq * 8];
#pragma unroll
    for (int nn = 0; nn < 8; ++nn) {
      h8 bf = *(const h8*)&Bt[n0 + nn * 16 + lm][lq * 8];
#pragma unroll
      for (int mm = 0; mm < 4; ++mm)
        acc[mm][nn] = __builtin_amdgcn_mfma_f32_16x16x32_f16(af[mm], bf, acc[mm][nn], 0, 0, 0);
    }
    __syncthreads();
  }
#pragma unroll
  for (int nn = 0; nn < 8; ++nn) {
    int col = n0 + nn * 16 + lm;
    float bv = bias[col];
#pragma unroll
    for (int mm = 0; mm < 4; ++mm) {
#pragma unroll
      for (int r = 0; r < 4; ++r) {
        int row = m0 + mm * 16 + lq * 4 + r;
        C[(size_t)row * HID + col] = (_Float16)(acc[mm][nn][r] + bv);
      }
    }
  }
}

// ---------------- recurrence kernel (M=1 MFMA, 8 waves, 2/SIMD) ----------------
template <bool WRITE_H, bool DO_FC>
__global__ __launch_bounds__(512, 2) void rec_kernel(
    const _Float16* __restrict__ P, _Float16* __restrict__ Pout,
    const uint4* __restrict__ BregP, const uint4* __restrict__ BldsP,
    const float* __restrict__ Wfc, const float* __restrict__ bfc, float* __restrict__ out) {
  __shared__ __align__(16) uint4 Blds[NWAVE * NLDSF * 64];  // 147456 B
  __shared__ __align__(16) _Float16 hbuf[2][HID];           // 2 KB, double-buffered
  __shared__ float red[NWAVE];
  const int tid = threadIdx.x;
  const int b = blockIdx.x;
  const int w = tid >> 6, l = tid & 63, lq = l >> 4;

  // one-time loads. breg_a consumed ONLY as asm "a" operands -> AGPRs (128);
  // breg_v as "v" -> VGPRs (56). No per-use moves (round-2 lesson).
  h8 breg_a[NAG];
#pragma unroll
  for (int i = 0; i < NAG; ++i)
    breg_a[i] = __builtin_bit_cast(h8, BregP[(w * NREGF + i) * 64 + l]);
  h8 breg_v[NVG];
#pragma unroll
  for (int i = 0; i < NVG; ++i)
    breg_v[i] = __builtin_bit_cast(h8, BregP[(w * NREGF + NAG + i) * 64 + l]);
#pragma unroll
  for (int j = 0; j < NLDSF; ++j)
    Blds[(w * NLDSF + j) * 64 + l] = BldsP[(w * NLDSF + j) * 64 + l];

  ((unsigned short*)hbuf[0])[tid] = 0;   // h0 = 0 (buffer 1 written before read)
  __syncthreads();

  const _Float16* prow = P + (size_t)b * TSEQ * HID;
  unsigned short xp_cur = *(const unsigned short*)(prow + tid);
  float lv = 0.f;

#pragma unroll 1
  for (int t = 0; t < TSEQ; ++t) {
    int tn = (t + 1 < TSEQ) ? t + 1 : t;
    unsigned short xp_next = *(const unsigned short*)(prow + (size_t)tn * HID + tid);
    const _Float16* hb = hbuf[t & 1];

    f4 acc[4];
#pragma unroll
    for (int g = 0; g < 4; ++g) acc[g] = (f4){0.f, 0.f, 0.f, 0.f};

#pragma unroll
    for (int kk = 0; kk < 16; ++kk) {
      // A-frag: h replicated into 16 rows (quad-uniform address -> broadcast)
      h8 a = *(const h8*)(hb + kk * 32 + lq * 8);
      MFMA_A(acc[0], a, breg_a[2 * kk]);
      MFMA_A(acc[1], a, breg_a[2 * kk + 1]);
      if (kk < 14) {
        MFMA_V(acc[2], a, breg_v[kk]);
      } else {
        h8 bf = __builtin_bit_cast(h8, Blds[(w * NLDSF + 16 + (kk - 14)) * 64 + l]);
        MFMA_V(acc[2], a, bf);
      }
      {
        h8 bf = __builtin_bit_cast(h8, Blds[(w * NLDSF + kk) * 64 + l]);
        MFMA_V(acc[3], a, bf);
      }
    }

    // NO LDS exchange: with broadcast-A all C rows are equal, so every lane's
    // acc[g][0] = col 16g+(l&15) of tile g. Lane l picks g = l>>4 = lq:
    // h[64w + l] = acc[lq][0]. cndmask chain keeps acc in registers.
    float hr = (lq == 0) ? acc[0][0]
             : (lq == 1) ? acc[1][0]
             : (lq == 2) ? acc[2][0]
                         : acc[3][0];

    // fast tanh: tanh(s) = 1 - 2/(exp(2s)+1); NaN-free for all finite s.
    float sum = hr + (float)__builtin_bit_cast(_Float16, xp_cur);
    float ev = __expf(2.0f * sum);
    float v = 1.0f - 2.0f * FAST_RCP(ev + 1.0f);
    lv = v;
    _Float16 hw = (_Float16)v;
    *(_Float16*)(&hbuf[(t + 1) & 1][tid]) = hw;
    if (WRITE_H)
      *(Pout + (size_t)b * TSEQ * HID + (size_t)t * HID + tid) = hw;
    __syncthreads();   // single barrier per step (hbuf double-buffered)
    xp_cur = xp_next;
  }

  if (DO_FC) {
    float fc = lv * Wfc[tid];
#pragma unroll
    for (int off = 32; off; off >>= 1) fc += __shfl_down(fc, off, 64);
    if (l == 0) red[w] = fc;
    __syncthreads();
    if (tid == 0) {
      float s = bfc[0];
#pragma unroll
      for (int i = 0; i < NWAVE; ++i) s += red[i];
      out[b] = s;
    }
  }
}

// ---------------- launcher ----------------
extern "C" void kernel_launch(void* const* d_in, const int* in_sizes, int n_in,
                              void* d_out, int out_size, void* d_ws, size_t ws_size,
                              hipStream_t stream) {
  const float* x    = (const float*)d_in[0];
  const float* Wih0 = (const float*)d_in[1];
  const float* Whh0 = (const float*)d_in[2];
  const float* bih0 = (const float*)d_in[3];
  const float* bhh0 = (const float*)d_in[4];
  const float* Wih1 = (const float*)d_in[5];
  const float* Whh1 = (const float*)d_in[6];
  const float* bih1 = (const float*)d_in[7];
  const float* bhh1 = (const float*)d_in[8];
  const float* Wfc  = (const float*)d_in[9];
  const float* bfc  = (const float*)d_in[10];
  float* out = (float*)d_out;
  char* ws = (char*)d_ws;

  _Float16* P  = (_Float16*)(ws + OFF_P);
  _Float16* B0 = (_Float16*)(ws + OFF_B0);
  _Float16* B1 = (_Float16*)(ws + OFF_B1);
  uint4* R0 = (uint4*)(ws + OFF_R0);
  uint4* L0 = (uint4*)(ws + OFF_L0);
  uint4* R1 = (uint4*)(ws + OFF_R1);
  uint4* L1 = (uint4*)(ws + OFF_L1);
  float* bias0 = (float*)(ws + OFF_BS0);
  float* bias1 = (float*)(ws + OFF_BS1);

  bias_kernel<<<1, 512, 0, stream>>>(bih0, bhh0, bih1, bhh1, bias0, bias1);
  cvt_half_kernel<<<128, 256, 0, stream>>>(Wih0, B0, 512 * 64);
  cvt_half_kernel<<<1024, 256, 0, stream>>>(Wih1, B1, 512 * 512);
  pack_rec_kernel<<<128, 256, 0, stream>>>(Whh0, R0, L0);
  pack_rec_kernel<<<128, 256, 0, stream>>>(Whh1, R1, L1);

  proj_kernel<float, 64><<<2048, 256, 0, stream>>>(x, B0, P, bias0);
  rec_kernel<true, false><<<NB, 512, 0, stream>>>(P, P, R0, L0, nullptr, nullptr, nullptr);
  proj_kernel<_Float16, 512><<<2048, 256, 0, stream>>>(P, B1, P, bias1);
  rec_kernel<false, true><<<NB, 512, 0, stream>>>(P, nullptr, R1, L1, Wfc, bfc, out);
}